// Round 1
// baseline (285.467 us; speedup 1.0000x reference)
//
#include <hip/hip_runtime.h>

#define BB 256
#define NP 12
#define TT 20
#define DD 512
#define EPS_A 1e-6f
#define EPS_BN 1e-5f
#define THR2 (150.0f * 150.0f)
#define APITCH 520            // ushorts per A-tile row: 1040 B, 16B-aligned, bank stride 4 dw -> <=2-way (free)
#define COPY_TOTAL 7864320L   // pf/out size in float4 units (256*12*20*512/4)
#define C0 491520L            // prep kernel copies [0, C0)
#define NCPY 1792             // copy blocks in fused kernel

typedef __attribute__((ext_vector_type(8))) short shortx8;
typedef __attribute__((ext_vector_type(4))) float floatx4;

static __device__ __forceinline__ ushort f2bf(float f) {
    unsigned x = __float_as_uint(f);
    return (ushort)((x + 0x7fffu + ((x >> 16) & 1u)) >> 16);  // RNE
}

// grid-stride float4 copy of [lo,hi), always skipping t==19 rows (compute blocks write them)
static __device__ __forceinline__ void copy_body(int cb, int ncb, long lo, long hi,
                                                 const float4* __restrict__ src,
                                                 float4* __restrict__ dst) {
    long stride = (long)ncb * 256;
    for (long g = lo + (long)cb * 256 + threadIdx.x; g < hi; g += stride) {
        int row = (int)(g >> 7);           // 128 float4 per 512-float row
        if (row % TT == TT - 1) continue;  // slice rows: written by fused compute blocks
        dst[g] = src[g];
    }
}

// ---------------------------------------------------------------------------
// prep: [0,64) cast W1,W2 -> bf16 ; [64] BN scale/shift vecs ; [65,256) copy chunk
// ---------------------------------------------------------------------------
__global__ __launch_bounds__(256) void k_prep(
    const float* __restrict__ W1, const float* __restrict__ W2,
    const float* __restrict__ b1, const float* __restrict__ g1,
    const float* __restrict__ beta1, const float* __restrict__ m1, const float* __restrict__ v1,
    const float* __restrict__ b2, const float* __restrict__ g2,
    const float* __restrict__ beta2, const float* __restrict__ m2, const float* __restrict__ v2,
    float* __restrict__ s1, float* __restrict__ t1, float* __restrict__ s2, float* __restrict__ t2,
    ushort* __restrict__ wb1, ushort* __restrict__ wb2,
    const float4* __restrict__ csrc, float4* __restrict__ cdst) {
    int bid = blockIdx.x, t = threadIdx.x;
    if (bid < 64) {  // 131072 float4 total (W1 then W2)
        int idx = bid * 256 + t;
        for (int i = idx; i < 131072; i += 16384) {
            float4 f = (i < 65536) ? ((const float4*)W1)[i] : ((const float4*)W2)[i - 65536];
            ushort4 u;
            u.x = f2bf(f.x); u.y = f2bf(f.y); u.z = f2bf(f.z); u.w = f2bf(f.w);
            if (i < 65536) *(ushort4*)(wb1 + (long)i * 4) = u;
            else           *(ushort4*)(wb2 + (long)(i - 65536) * 4) = u;
        }
    } else if (bid == 64) {
        for (int d = t; d < DD; d += 256) {
            float sa = g1[d] * rsqrtf(v1[d] + EPS_BN);
            s1[d] = sa; t1[d] = (b1[d] - m1[d]) * sa + beta1[d];
            float sb = g2[d] * rsqrtf(v2[d] + EPS_BN);
            s2[d] = sb; t2[d] = (b2[d] - m2[d]) * sb + beta2[d];
        }
    } else {
        copy_body(bid - 65, 191, 0L, C0, csrc, cdst);
    }
}

// ---------------------------------------------------------------------------
// Per-batch GEMM: full M=12 (one 16-row tile), N=512 split 4 waves x 8 n-tiles,
// K=512. A from LDS tile, B fragments read DIRECTLY from global bf16 W (L2-hot).
// LAYER 1 -> y1l (LDS fp32) ; LAYER 2 -> out slice rows.
// ---------------------------------------------------------------------------
template <int LAYER>
static __device__ __forceinline__ void gemm16(
    int wave, int lane, int b,
    const ushort (*__restrict__ xgl)[APITCH], float (*__restrict__ y1l)[DD],
    const ushort* __restrict__ wb, const float* __restrict__ sv, const float* __restrict__ tv,
    float* __restrict__ outp) {
    int mrow = lane & 15, quad = lane >> 4;
    floatx4 acc[8];
    #pragma unroll
    for (int nt = 0; nt < 8; nt++) acc[nt] = (floatx4){0.f, 0.f, 0.f, 0.f};

    const ushort* wbase = wb + ((long)(wave * 128 + mrow)) * DD + quad * 8;
    #pragma unroll 2
    for (int kc = 0; kc < DD; kc += 32) {
        shortx8 af = *(const shortx8*)&xgl[mrow][kc + quad * 8];
        #pragma unroll
        for (int nt = 0; nt < 8; nt++) {
            shortx8 bf = *(const shortx8*)(wbase + nt * 16 * DD + kc);
            acc[nt] = __builtin_amdgcn_mfma_f32_16x16x32_bf16(af, bf, acc[nt], 0, 0, 0);
        }
    }

    #pragma unroll
    for (int nt = 0; nt < 8; nt++) {
        int d = wave * 128 + nt * 16 + mrow;
        float s = sv[d], tt = tv[d];
        #pragma unroll
        for (int v = 0; v < 4; v++) {
            int m = quad * 4 + v;
            float val = fmaxf(acc[nt][v] * s + tt, 0.f);
            if (m < NP) {
                if (LAYER == 1) y1l[m][d] = val;
                else outp[((long)(b * NP + m) * TT + TT - 1) * DD + d] = val;
            }
        }
    }
}

// ---------------------------------------------------------------------------
// fused: blocks [0,256) run full per-batch STGCN chain in LDS;
//        blocks [256, 256+NCPY) stream the big pf->out copy concurrently.
// ---------------------------------------------------------------------------
__global__ __launch_bounds__(256) void k_fused(
    const float* __restrict__ pf, const float* __restrict__ bboxes,
    const ushort* __restrict__ wb1, const ushort* __restrict__ wb2,
    const float* __restrict__ s1, const float* __restrict__ t1,
    const float* __restrict__ s2, const float* __restrict__ t2,
    float* __restrict__ out,
    const float4* __restrict__ csrc, float4* __restrict__ cdst) {
    __shared__ float cx[NP], cy[NP], Ash[NP][NP], rinv[NP], at[NP][NP];
    __shared__ __align__(16) ushort xgl[16][APITCH];  // bf16 A-tile (rows 12..15 zero)
    __shared__ float y1l[NP][DD];                     // fp32 layer-1 output

    int bid = blockIdx.x, t = threadIdx.x;
    if (bid >= BB) {
        copy_body(bid - BB, NCPY, C0, COPY_TOTAL, csrc, cdst);
        return;
    }

    int b = bid;
    int lane = t & 63, wave = t >> 6;

    // ---- adjacency ----
    if (t < NP) {
        const float* p = bboxes + (b * NP + t) * 4;
        cx[t] = p[0] + 0.5f * p[2];
        cy[t] = p[1] + 0.5f * p[3];
    }
    // zero pad rows 12..15 of xgl (read by MFMA, must be 0)
    {
        uint* xz = (uint*)&xgl[NP][0];
        for (int i = t; i < 4 * APITCH / 2; i += 256) xz[i] = 0;
    }
    __syncthreads();
    if (t < NP * NP) {
        int n = t / NP, k = t % NP;
        float dx = cx[n] - cx[k], dy = cy[n] - cy[k];
        Ash[n][k] = (dx * dx + dy * dy < THR2) ? 1.f : 0.f;
    }
    __syncthreads();
    if (t < NP) {
        float s = 0.f;
        #pragma unroll
        for (int k = 0; k < NP; k++) s += Ash[t][k];
        rinv[t] = 1.f / (s + EPS_A);
    }
    __syncthreads();
    if (t < NP * NP) {
        int j = t / NP, n = t % NP;
        at[j][n] = Ash[n][j] * rinv[n];
    }
    __syncthreads();

    // ---- mix1: pf last slice -> xgl (bf16) ----
    for (int c = t; c < DD; c += 256) {
        float xv[NP];
        #pragma unroll
        for (int n = 0; n < NP; n++)
            xv[n] = pf[((long)((b * NP + n) * TT + TT - 1)) * DD + c];
        #pragma unroll
        for (int j = 0; j < NP; j++) {
            float a = 0.f;
            #pragma unroll
            for (int n = 0; n < NP; n++) a += at[j][n] * xv[n];
            xgl[j][c] = f2bf(a);
        }
    }
    __syncthreads();

    // ---- layer 1 GEMM + BN + relu -> y1l ----
    gemm16<1>(wave, lane, b, xgl, y1l, wb1, s1, t1, nullptr);
    __syncthreads();

    // ---- mix2: y1l -> xgl (bf16) ----
    for (int c = t; c < DD; c += 256) {
        float xv[NP];
        #pragma unroll
        for (int n = 0; n < NP; n++) xv[n] = y1l[n][c];
        #pragma unroll
        for (int j = 0; j < NP; j++) {
            float a = 0.f;
            #pragma unroll
            for (int n = 0; n < NP; n++) a += at[j][n] * xv[n];
            xgl[j][c] = f2bf(a);
        }
    }
    __syncthreads();

    // ---- layer 2 GEMM + BN + relu -> out slice rows ----
    gemm16<2>(wave, lane, b, xgl, y1l, wb2, s2, t2, out);
}

// ---------------------------------------------------------------------------
extern "C" void kernel_launch(void* const* d_in, const int* in_sizes, int n_in,
                              void* d_out, int out_size, void* d_ws, size_t ws_size,
                              hipStream_t stream) {
    const float* pf = (const float*)d_in[0];
    const float* bboxes = (const float*)d_in[1];
    const float* W1 = (const float*)d_in[2];
    const float* b1 = (const float*)d_in[3];
    const float* g1 = (const float*)d_in[4];
    const float* beta1 = (const float*)d_in[5];
    const float* m1 = (const float*)d_in[6];
    const float* v1 = (const float*)d_in[7];
    const float* W2 = (const float*)d_in[8];
    const float* b2 = (const float*)d_in[9];
    const float* g2 = (const float*)d_in[10];
    const float* beta2 = (const float*)d_in[11];
    const float* m2 = (const float*)d_in[12];
    const float* v2 = (const float*)d_in[13];
    float* out = (float*)d_out;

    float* ws = (float*)d_ws;
    float* s1 = ws;
    float* t1v = ws + 512;
    float* s2 = ws + 1024;
    float* t2v = ws + 1536;
    ushort* wb1 = (ushort*)(ws + 2048);   // 262144 ushorts
    ushort* wb2 = wb1 + 262144;           // 262144 ushorts

    const float4* csrc = (const float4*)pf;
    float4* cdst = (float4*)out;

    k_prep<<<256, 256, 0, stream>>>(W1, W2, b1, g1, beta1, m1, v1,
                                    b2, g2, beta2, m2, v2,
                                    s1, t1v, s2, t2v, wb1, wb2, csrc, cdst);
    k_fused<<<BB + NCPY, 256, 0, stream>>>(pf, bboxes, wb1, wb2,
                                           s1, t1v, s2, t2v, out, csrc, cdst);
}